// Round 4
// baseline (113.000 us; speedup 1.0000x reference)
//
#include <hip/hip_runtime.h>
#include <math.h>

#define BB 4
#define CC 128
#define HW 4096
// sqrt(10 * log2(e)) — folds 1/tau AND exp->exp2 into both normalized sides:
// sim' = sim * log2(e), so exp(sim) == exp2(sim').
#define SCF 3.798282565f

typedef short short8 __attribute__((ext_vector_type(8)));
typedef float f32x4 __attribute__((ext_vector_type(4)));

static __device__ inline unsigned short f2bf(float f) {
  // round-to-nearest-even fp32 -> bf16 (inputs are finite)
  unsigned int u = __float_as_uint(f);
  u += 0x7fffu + ((u >> 16) & 1u);
  return (unsigned short)(u >> 16);
}

// K1: per 32-position tile: inv-norms of A and B, fp32 diagonal similarity,
// zero expsum + completion counter, and write bf16 normalized*SCF features
// transposed to [b][pos][c] with XOR-swizzled 16B chunks (position q holds
// data chunk q^(n&7)) so k_main's global_load_lds staging is an identity copy
// while MFMA fragment ds_reads stay 2-way-conflict (free).
__global__ __launch_bounds__(256) void k_prep(const float* __restrict__ fA,
                                              const float* __restrict__ fB,
                                              unsigned short* __restrict__ fAn,
                                              unsigned short* __restrict__ fBn,
                                              float* __restrict__ diag,
                                              float* __restrict__ expsum,
                                              float* __restrict__ acc) {
  __shared__ float sA[32 * 129];
  __shared__ float sB[32 * 129];
  __shared__ float red[3 * 256];

  const int bid = blockIdx.x;          // 0..511 : b*128 + tile
  const int b   = bid >> 7;
  const int n0  = (bid & 127) * 32;
  const int tid = threadIdx.x;
  const int cR  = tid >> 5;            // 0..7
  const int n   = tid & 31;            // 0..31

  if (bid == 0 && tid == 0) { acc[0] = 0.f; acc[1] = 0.f; ((unsigned*)acc)[2] = 0u; }

  const float* pa = fA + (size_t)b * CC * HW + n0 + n;
  const float* pb = fB + (size_t)b * CC * HW + n0 + n;

  float ssa = 0.f, ssb = 0.f, dot = 0.f;
  #pragma unroll
  for (int it = 0; it < 16; ++it) {
    int c = it * 8 + cR;
    float va = pa[(size_t)c * HW];
    float vb = pb[(size_t)c * HW];
    sA[n * 129 + c] = va;
    sB[n * 129 + c] = vb;
    ssa = fmaf(va, va, ssa);
    ssb = fmaf(vb, vb, ssb);
    dot = fmaf(va, vb, dot);
  }
  red[tid] = ssa; red[256 + tid] = ssb; red[512 + tid] = dot;
  __syncthreads();

  if (tid < 32) {
    float sa = 0.f, sb = 0.f, dt = 0.f;
    #pragma unroll
    for (int k = 0; k < 8; ++k) {
      sa += red[k * 32 + tid];
      sb += red[256 + k * 32 + tid];
      dt += red[512 + k * 32 + tid];
    }
    float ia = 1.f / fmaxf(sqrtf(sa), 1e-12f);
    float ib = 1.f / fmaxf(sqrtf(sb), 1e-12f);
    int gidx = b * HW + n0 + tid;
    diag[gidx]   = dt * ia * ib * 10.f;   // true sim scale (1/tau)
    expsum[gidx] = 0.f;
    red[tid]      = ia * SCF;   // sole reader/writer of these slots
    red[32 + tid] = ib * SCF;
  }
  __syncthreads();

  #pragma unroll
  for (int r = 0; r < 2; ++r) {
    int L  = r * 256 + tid;
    int nn = L >> 4;                  // 0..31
    int q  = L & 15;                  // store position within row
    int c0 = (q ^ (nn & 7)) * 8;      // data chunk (swizzle)
    size_t base = ((size_t)b * HW + n0 + nn) * 128 + q * 8;
    {
      float sc = red[nn];
      const float* s = &sA[nn * 129 + c0];
      uint4 v;
      v.x = f2bf(s[0]*sc) | ((unsigned)f2bf(s[1]*sc) << 16);
      v.y = f2bf(s[2]*sc) | ((unsigned)f2bf(s[3]*sc) << 16);
      v.z = f2bf(s[4]*sc) | ((unsigned)f2bf(s[5]*sc) << 16);
      v.w = f2bf(s[6]*sc) | ((unsigned)f2bf(s[7]*sc) << 16);
      *(uint4*)(fAn + base) = v;
    }
    {
      float sc = red[32 + nn];
      const float* s = &sB[nn * 129 + c0];
      uint4 v;
      v.x = f2bf(s[0]*sc) | ((unsigned)f2bf(s[1]*sc) << 16);
      v.y = f2bf(s[2]*sc) | ((unsigned)f2bf(s[3]*sc) << 16);
      v.z = f2bf(s[4]*sc) | ((unsigned)f2bf(s[5]*sc) << 16);
      v.w = f2bf(s[6]*sc) | ((unsigned)f2bf(s[7]*sc) << 16);
      *(uint4*)(fBn + base) = v;
    }
  }
}

// K2: B-resident MFMA GEMM with B-fragments held in registers, ping-pong
// A-prefetch (global_load_lds issued after frag reads, before compute, so the
// MFMA+exp phase has no LDS deps and the prefetch lands during compute), fused
// exp2 column-sum epilogue, and last-block loss finish.
__global__ __launch_bounds__(256, 2) void k_main(const unsigned short* __restrict__ fAn,
                                                 const unsigned short* __restrict__ fBn,
                                                 float* __restrict__ expsum,
                                                 const float* __restrict__ diag,
                                                 const float* __restrict__ mask,
                                                 float* __restrict__ acc,
                                                 float* __restrict__ out) {
  __shared__ unsigned short lds[2 * 16384];   // 64 KB: two 128x128 bf16 buffers
  unsigned short* buf0 = lds;
  unsigned short* buf1 = lds + 16384;
  __shared__ bool lastFlag;

  const int bid = blockIdx.x;                // 0..511
  const int x   = bid & 7;                   // XCD
  const int t   = bid >> 3;                  // 0..63
  const int b   = x & 3;
  const int nq  = (x >> 2) | ((t & 1) << 1); // 0..3
  const int mt  = t >> 1;                    // 0..31
  const int m0  = mt * 128;
  const int nbase = nq * 1024;
  const int tid = threadIdx.x;

  const int wv   = tid >> 6;
  const int lane = tid & 63;
  const int ml   = lane & 15;
  const int g    = lane >> 4;
  const int wn   = (wv & 1) * 64;    // wave n-offset within A chunk
  const int wm   = (wv >> 1) * 64;   // wave m-offset within B tile

  auto stage = [&](const unsigned short* gsrc, unsigned short* dst) {
    #pragma unroll
    for (int r = 0; r < 8; ++r) {
      int L = r * 256 + tid;
      __builtin_amdgcn_global_load_lds(
          (const __attribute__((address_space(1))) unsigned int*)(gsrc + (size_t)L * 8),
          (__attribute__((address_space(3))) unsigned int*)(dst + L * 8), 16, 0, 0);
    }
  };
  const unsigned short* gAbase = fAn + ((size_t)b * HW + nbase) * 128;

  // initial staging: B tile -> buf1, A chunk 0 -> buf0
  stage(fBn + ((size_t)b * HW + m0) * 128, buf1);
  stage(gAbase, buf0);
  __syncthreads();

  short8 bf[4][4], af[4][4];
  #pragma unroll
  for (int kc = 0; kc < 4; ++kc) {
    int q = kc * 4 + g;
    #pragma unroll
    for (int j = 0; j < 4; ++j) {
      int nb = wm + j * 16 + ml;
      bf[kc][j] = *(const short8*)(buf1 + nb * 128 + ((q ^ (nb & 7)) * 8));
    }
    #pragma unroll
    for (int i = 0; i < 4; ++i) {
      int na = wn + i * 16 + ml;
      af[kc][i] = *(const short8*)(buf0 + na * 128 + ((q ^ (na & 7)) * 8));
    }
  }
  __syncthreads();                 // all waves done reading B from buf1
  stage(gAbase + (size_t)1 * 16384, buf1);   // prefetch A1 (overlaps it0 compute)

  float colAcc[4] = {0.f, 0.f, 0.f, 0.f};

  for (int it = 0; it < 8; ++it) {
    // compute phase: no LDS accesses -> prefetch stays in flight
    f32x4 acc4[4][4] = {};
    #pragma unroll
    for (int kc = 0; kc < 4; ++kc)
      #pragma unroll
      for (int i = 0; i < 4; ++i)
        #pragma unroll
        for (int j = 0; j < 4; ++j)
          acc4[i][j] = __builtin_amdgcn_mfma_f32_16x16x32_bf16(af[kc][i], bf[kc][j], acc4[i][j], 0, 0, 0);
    // epilogue: per-column sums of exp2(sim'). C layout: col=lane&15, row=g*4+r.
    // |sim'| <= 14.43 -> exp2 within fp32 range, no shift needed.
    #pragma unroll
    for (int j = 0; j < 4; ++j) {
      float e = 0.f;
      #pragma unroll
      for (int i = 0; i < 4; ++i)
        #pragma unroll
        for (int r = 0; r < 4; ++r)
          e += exp2f(acc4[i][j][r]);
      colAcc[j] += e;
    }
    if (it == 7) break;
    __syncthreads();               // A(it+1) resident; prior buffer reads done
    const unsigned short* bufc = (it & 1) ? buf0 : buf1;   // buf[(it+1)&1]
    #pragma unroll
    for (int kc = 0; kc < 4; ++kc) {
      int q = kc * 4 + g;
      #pragma unroll
      for (int i = 0; i < 4; ++i) {
        int na = wn + i * 16 + ml;
        af[kc][i] = *(const short8*)(bufc + na * 128 + ((q ^ (na & 7)) * 8));
      }
    }
    if (it < 6)
      stage(gAbase + (size_t)(it + 2) * 16384, (it & 1) ? buf1 : buf0);
  }

  // per-column reduce across row-groups, one atomic per column
  #pragma unroll
  for (int j = 0; j < 4; ++j) {
    float e = colAcc[j];
    e += __shfl_xor(e, 16, 64);
    e += __shfl_xor(e, 32, 64);
    if (lane < 16)
      atomicAdd(&expsum[(size_t)b * HW + m0 + wm + j * 16 + lane], e);
  }

  // last-block loss finish
  __syncthreads();                 // drains all atomics (vmcnt) block-wide
  if (tid == 0) {
    __threadfence();
    lastFlag = (atomicAdd((unsigned*)(acc + 2), 1u) == 511u);
  }
  __syncthreads();
  if (lastFlag) {
    float num = 0.f, den = 0.f;
    #pragma unroll 4
    for (int i = tid; i < BB * HW; i += 256) {
      float es = __hip_atomic_load(expsum + i, __ATOMIC_RELAXED, __HIP_MEMORY_SCOPE_AGENT);
      float mv = mask[i];
      num = fmaf(mv, __logf(es) - diag[i], num);   // ln(sum exp(sim)) - sim_kk
      den += mv;
    }
    #pragma unroll
    for (int off = 32; off; off >>= 1) {
      num += __shfl_down(num, off, 64);
      den += __shfl_down(den, off, 64);
    }
    float* red = (float*)lds;
    if (lane == 0) { red[wv] = num; red[8 + wv] = den; }
    __syncthreads();
    if (tid == 0) {
      float n = red[0] + red[1] + red[2] + red[3];
      float d = red[8] + red[9] + red[10] + red[11];
      out[0] = n / (d + 1e-6f);
    }
  }
}

extern "C" void kernel_launch(void* const* d_in, const int* in_sizes, int n_in,
                              void* d_out, int out_size, void* d_ws, size_t ws_size,
                              hipStream_t stream) {
  const float* feat_A = (const float*)d_in[0];
  const float* feat_B = (const float*)d_in[1];
  // d_in[2] = H_mat : unused by the reference computation
  const float* vmask  = (const float*)d_in[3];

  unsigned short* fAn = (unsigned short*)d_ws;            // 4 MB bf16 [b][n][c] swizzled
  unsigned short* fBn = fAn + (size_t)BB * HW * CC;       // 4 MB
  float* diag   = (float*)(fBn + (size_t)BB * HW * CC);   // 64 KB
  float* expsum = diag + BB * HW;                         // 64 KB
  float* acc    = expsum + BB * HW;                       // num, den, counter
  float* out    = (float*)d_out;

  k_prep<<<512, 256, 0, stream>>>(feat_A, feat_B, fAn, fBn, diag, expsum, acc);
  k_main<<<512, 256, 0, stream>>>(fAn, fBn, expsum, diag, vmask, acc, out);
}